// Round 1
// baseline (1180.869 us; speedup 1.0000x reference)
//
#include <hip/hip_runtime.h>
#include <hip/hip_bf16.h>
#include <math.h>

#define NN 25000
#define NE 250000
#define DD 64
#define HH 4

__device__ __forceinline__ float softplus_f(float x) {
    return fmaxf(x, 0.0f) + log1pf(__expf(-fabsf(x)));
}

__device__ __forceinline__ float rdlane(float v, int k) {
    return __int_as_float(__builtin_amdgcn_readlane(__float_as_int(v), k));
}

__device__ __forceinline__ unsigned short f2bf(float f) {
    __hip_bfloat16 h = __float2bfloat16(f);
    unsigned short u;
    __builtin_memcpy(&u, &h, 2);
    return u;
}

__device__ __forceinline__ float bf2f(unsigned short u) {
    return __uint_as_float(((unsigned int)u) << 16);
}

// Epilogue for one edge: softplus, attention logit, wave-reduce, BN+softplus,
// exp, denom atomic, store exp_alpha and bf16 out_j.
#define EDGE_EPILOGUE(AXI, AXJ, AE, EDGE, IDX)                                   \
    {                                                                            \
        float spj[4], pr[4];                                                     \
        _Pragma("unroll")                                                        \
        for (int t = 0; t < 4; ++t) {                                            \
            float si = softplus_f(AXI[t] + AE[t]);                               \
            float sj = softplus_f(AXJ[t] + AE[t]);                               \
            spj[t] = sj;                                                         \
            pr[t] = si * atti[t] + sj * attj[t];                                 \
        }                                                                        \
        _Pragma("unroll")                                                        \
        for (int off = 32; off > 0; off >>= 1) {                                 \
            _Pragma("unroll")                                                    \
            for (int t = 0; t < 4; ++t) pr[t] += __shfl_xor(pr[t], off, 64);     \
        }                                                                        \
        float ex[4];                                                             \
        _Pragma("unroll")                                                        \
        for (int t = 0; t < 4; ++t)                                              \
            ex[t] = __expf(softplus_f(fmaf(pr[t], bnsc[t], bnsh[t])));           \
        if (lane == 0) {                                                         \
            *(float4*)&expa[(EDGE) * 4] = make_float4(ex[0], ex[1], ex[2], ex[3]); \
            _Pragma("unroll")                                                    \
            for (int t = 0; t < 4; ++t) atomicAdd(&denom[(IDX) * 4 + t], ex[t]); \
        }                                                                        \
        ushort4 pk;                                                              \
        pk.x = f2bf(spj[0]); pk.y = f2bf(spj[1]);                                \
        pk.z = f2bf(spj[2]); pk.w = f2bf(spj[3]);                                \
        *(ushort4*)&outj[((unsigned)(EDGE) << 8) | (lane << 2)] = pk;            \
    }

// Wave processes 2 edges. W (128x256) lives in LDS as bf16, swizzled so that
// lane l's 4 output columns {l, l+64, l+128, l+192} = (head t, dim d=l) are one
// contiguous 8B read. A-values broadcast via v_readlane (SGPR operand to FMA).
// The edge_attr half of the GEMV is shared between the i- and j-row (25% FLOP cut).
__global__ __launch_bounds__(512, 4)
void k_edge(const float* __restrict__ x, const float* __restrict__ ea,
            const float* __restrict__ W, const float* __restrict__ att,
            const float* __restrict__ bn_g, const float* __restrict__ bn_b,
            const float* __restrict__ bn_m, const float* __restrict__ bn_v,
            const int* __restrict__ eidx,
            unsigned short* __restrict__ outj,
            float* __restrict__ expa, float* __restrict__ denom)
{
    __shared__ unsigned short Wsh[32768];   // 64 KiB exactly -> 2 blocks/CU
    const int tid = threadIdx.x;
    const int lane = tid & 63;
    const int wave = tid >> 6;

    for (int idx = tid; idx < 32768; idx += 512) {
        int k = idx >> 8, c = idx & 255;
        // dst col: 4*(c&63) + (c>>6)  => lane l reads cols {l, l+64, l+128, l+192}
        Wsh[(k << 8) | ((c & 63) << 2) | (c >> 6)] = f2bf(W[idx]);
    }

    float atti[HH], attj[HH], bnsc[HH], bnsh[HH];
#pragma unroll
    for (int t = 0; t < HH; ++t) {
        atti[t] = att[t * 128 + lane];
        attj[t] = att[t * 128 + 64 + lane];
        float inv = rsqrtf(bn_v[t] + 1e-5f);
        bnsc[t] = bn_g[t] * inv;
        bnsh[t] = bn_b[t] - bn_m[t] * bn_g[t] * inv;
    }
    __syncthreads();

    const int gw = blockIdx.x * 8 + wave;
    const int nw = gridDim.x * 8;
    for (int p = gw; p < NE / 2; p += nw) {
        const int e0 = 2 * p, e1 = e0 + 1;
        const int i0 = eidx[e0], i1 = eidx[e1];
        const int j0 = eidx[NE + e0], j1 = eidx[NE + e1];
        const float xi0 = x[i0 * DD + lane];
        const float xj0 = x[j0 * DD + lane];
        const float xi1 = x[i1 * DD + lane];
        const float xj1 = x[j1 * DD + lane];
        const float ev0 = ea[e0 * DD + lane];
        const float ev1 = ea[e1 * DD + lane];

        float axi0[4] = {0.f, 0.f, 0.f, 0.f}, axj0[4] = {0.f, 0.f, 0.f, 0.f};
        float axi1[4] = {0.f, 0.f, 0.f, 0.f}, axj1[4] = {0.f, 0.f, 0.f, 0.f};
        float ae0[4] = {0.f, 0.f, 0.f, 0.f}, ae1[4] = {0.f, 0.f, 0.f, 0.f};

        // phase 1: k = 0..63, x-part (W rows 0..63)
#pragma unroll 8
        for (int k = 0; k < 64; ++k) {
            uint2 wp = *(const uint2*)&Wsh[(k << 8) | (lane << 2)];
            float w0 = __uint_as_float(wp.x << 16);
            float w1 = __uint_as_float(wp.x & 0xffff0000u);
            float w2 = __uint_as_float(wp.y << 16);
            float w3 = __uint_as_float(wp.y & 0xffff0000u);
            const float s0 = rdlane(xi0, k);
            const float s1 = rdlane(xj0, k);
            const float s2 = rdlane(xi1, k);
            const float s3 = rdlane(xj1, k);
            axi0[0] = fmaf(s0, w0, axi0[0]); axi0[1] = fmaf(s0, w1, axi0[1]);
            axi0[2] = fmaf(s0, w2, axi0[2]); axi0[3] = fmaf(s0, w3, axi0[3]);
            axj0[0] = fmaf(s1, w0, axj0[0]); axj0[1] = fmaf(s1, w1, axj0[1]);
            axj0[2] = fmaf(s1, w2, axj0[2]); axj0[3] = fmaf(s1, w3, axj0[3]);
            axi1[0] = fmaf(s2, w0, axi1[0]); axi1[1] = fmaf(s2, w1, axi1[1]);
            axi1[2] = fmaf(s2, w2, axi1[2]); axi1[3] = fmaf(s2, w3, axi1[3]);
            axj1[0] = fmaf(s3, w0, axj1[0]); axj1[1] = fmaf(s3, w1, axj1[1]);
            axj1[2] = fmaf(s3, w2, axj1[2]); axj1[3] = fmaf(s3, w3, axj1[3]);
        }
        // phase 2: edge_attr part (W rows 64..127), shared between i and j rows
#pragma unroll 8
        for (int k = 0; k < 64; ++k) {
            uint2 wp = *(const uint2*)&Wsh[((64 + k) << 8) | (lane << 2)];
            float w0 = __uint_as_float(wp.x << 16);
            float w1 = __uint_as_float(wp.x & 0xffff0000u);
            float w2 = __uint_as_float(wp.y << 16);
            float w3 = __uint_as_float(wp.y & 0xffff0000u);
            const float s0 = rdlane(ev0, k);
            const float s1 = rdlane(ev1, k);
            ae0[0] = fmaf(s0, w0, ae0[0]); ae0[1] = fmaf(s0, w1, ae0[1]);
            ae0[2] = fmaf(s0, w2, ae0[2]); ae0[3] = fmaf(s0, w3, ae0[3]);
            ae1[0] = fmaf(s1, w0, ae1[0]); ae1[1] = fmaf(s1, w1, ae1[1]);
            ae1[2] = fmaf(s1, w2, ae1[2]); ae1[3] = fmaf(s1, w3, ae1[3]);
        }

        EDGE_EPILOGUE(axi0, axj0, ae0, e0, i0)
        EDGE_EPILOGUE(axi1, axj1, ae1, e1, i1)
    }
}

// One wave per edge; lane = output dim d. Mean over heads folded in (0.25).
__global__ __launch_bounds__(256)
void k_scatter(const int* __restrict__ eidx,
               const unsigned short* __restrict__ outj,
               const float* __restrict__ expa,
               const float* __restrict__ denom,
               float* __restrict__ acc)
{
    const int e = blockIdx.x * 4 + (threadIdx.x >> 6);
    const int lane = threadIdx.x & 63;
    const int i = eidx[e];
    float4 ev = *(const float4*)&expa[e * 4];
    float4 dv = *(const float4*)&denom[i * 4];
    float w0 = 0.25f * ev.x / dv.x;
    float w1 = 0.25f * ev.y / dv.y;
    float w2 = 0.25f * ev.z / dv.z;
    float w3 = 0.25f * ev.w / dv.w;
    ushort4 v = *(const ushort4*)&outj[((unsigned)e << 8) | (lane << 2)];
    float s = w0 * bf2f(v.x) + w1 * bf2f(v.y) + w2 * bf2f(v.z) + w3 * bf2f(v.w);
    atomicAdd(&acc[i * DD + lane], s);
}

__global__ __launch_bounds__(256)
void k_final(const float* __restrict__ acc, const float* __restrict__ bias,
             float* __restrict__ out)
{
    const int t = blockIdx.x * 256 + threadIdx.x;
    out[t] = acc[t] + bias[t & 63];
}

extern "C" void kernel_launch(void* const* d_in, const int* in_sizes, int n_in,
                              void* d_out, int out_size, void* d_ws, size_t ws_size,
                              hipStream_t stream)
{
    (void)in_sizes; (void)n_in; (void)out_size; (void)ws_size;
    const float* x    = (const float*)d_in[0];
    const float* ea   = (const float*)d_in[1];
    const float* W    = (const float*)d_in[2];
    const float* att  = (const float*)d_in[3];
    const float* bias = (const float*)d_in[4];
    const float* bn_g = (const float*)d_in[5];
    const float* bn_b = (const float*)d_in[6];
    const float* bn_m = (const float*)d_in[7];
    const float* bn_v = (const float*)d_in[8];
    const int*   eidx = (const int*)d_in[9];
    float* out = (float*)d_out;

    // ws layout (all 16B-aligned):
    //   outj  bf16 [E][64][4]  : 128,000,000 B
    //   expa  f32  [E][4]      :   4,000,000 B
    //   denom f32  [N][4]      :     400,000 B
    //   acc   f32  [N][64]     :   6,400,000 B   total ~138.8 MB
    char* ws = (char*)d_ws;
    unsigned short* outj = (unsigned short*)ws;
    float* expa  = (float*)(ws + (size_t)NE * 256 * 2);
    float* denom = (float*)(ws + (size_t)NE * 256 * 2 + (size_t)NE * 16);
    float* acc   = denom + (size_t)NN * 4;

    hipMemsetAsync(denom, 0, (size_t)(NN * 4 + NN * DD) * sizeof(float), stream);

    k_edge<<<dim3(512), dim3(512), 0, stream>>>(
        x, ea, W, att, bn_g, bn_b, bn_m, bn_v, eidx, outj, expa, denom);
    k_scatter<<<dim3(NE / 4), dim3(256), 0, stream>>>(eidx, outj, expa, denom, acc);
    k_final<<<dim3((NN * DD) / 256), dim3(256), 0, stream>>>(acc, bias, out);
}

// Round 2
// 498.301 us; speedup vs baseline: 2.3698x; 2.3698x over previous
//
#include <hip/hip_runtime.h>
#include <hip/hip_bf16.h>
#include <math.h>

#define NN 25000
#define NE 250000
#define DD 64
#define HH 4
#define NGROUP (NE / 16)   // 15625 16-edge groups

typedef __attribute__((ext_vector_type(8))) short bf16x8;
typedef __attribute__((ext_vector_type(4))) float f32x4;

#define WT_LD 136   // 128 + 8 pad (shorts) -> 272B row stride, 2-way LDS conflict (free)

__device__ __forceinline__ float softplus_f(float x) {
    // max(x,0) + log(1+exp(-|x|)) ; __logf(1+t) is fine since t<=1
    return fmaxf(x, 0.0f) + __logf(1.0f + __expf(-fabsf(x)));
}

__device__ __forceinline__ unsigned short f2bf(float f) {
    __hip_bfloat16 h = __float2bfloat16(f);
    unsigned short u;
    __builtin_memcpy(&u, &h, 2);
    return u;
}

__device__ __forceinline__ float bf2f(unsigned short u) {
    return __uint_as_float(((unsigned int)u) << 16);
}

// Load 8 consecutive floats, split each into bf16 hi + bf16 lo (compensated).
__device__ __forceinline__ void load8(const float* p, bf16x8& hi, bf16x8& lo) {
    float4 a = *(const float4*)p;
    float4 b = *(const float4*)(p + 4);
    float v[8] = {a.x, a.y, a.z, a.w, b.x, b.y, b.z, b.w};
#pragma unroll
    for (int i = 0; i < 8; ++i) {
        unsigned short h = f2bf(v[i]);
        hi[i] = (short)h;
        lo[i] = (short)f2bf(v[i] - bf2f(h));
    }
}

// One wave = 16 edges. C_i = [x_i||ea] @ W, C_j = [x_j||ea] @ W via
// mfma_f32_16x16x32_bf16. A gathered straight into lanes (m=lane&15=edge,
// k=quad*8+j); W^T bf16 in LDS, B-frag = one ds_read_b128.
__global__ __launch_bounds__(256, 2)
void k_edge(const float* __restrict__ x, const float* __restrict__ ea,
            const float* __restrict__ W, const float* __restrict__ att,
            const float* __restrict__ bn_g, const float* __restrict__ bn_b,
            const float* __restrict__ bn_m, const float* __restrict__ bn_v,
            const int* __restrict__ eidx,
            unsigned short* __restrict__ outj,
            float* __restrict__ expa, float* __restrict__ denom)
{
    __shared__ unsigned short Wsh[256 * WT_LD];  // W^T bf16 [n][k], padded
    __shared__ float attI[256], attJ[256];

    const int tid = threadIdx.x;
    const int lane = tid & 63;
    const int q = lane >> 4;      // quad 0..3
    const int r = lane & 15;

    // Stage W^T (coalesced read of W[k*256+n], n fast-varying).
    for (int idx = tid; idx < 32768; idx += 256) {
        int k = idx >> 8, n = idx & 255;
        Wsh[n * WT_LD + k] = f2bf(W[idx]);
    }
    // att swizzled by output column c: attI[c] = att[head(c)][d(c)] (i-half).
    {
        int c = tid;  // 256 threads, 256 cols
        attI[c] = att[(c >> 6) * 128 + (c & 63)];
        attJ[c] = att[(c >> 6) * 128 + 64 + (c & 63)];
    }
    float bnsc[HH], bnsh[HH];
#pragma unroll
    for (int t = 0; t < HH; ++t) {
        float inv = rsqrtf(bn_v[t] + 1e-5f);
        bnsc[t] = bn_g[t] * inv;
        bnsh[t] = bn_b[t] - bn_m[t] * bn_g[t] * inv;
    }
    __syncthreads();

    const int gw = blockIdx.x * 4 + (tid >> 6);
    const int nw = gridDim.x * 4;

    for (int g = gw; g < NGROUP; g += nw) {
        const int e0 = g * 16;
        // ---- gather A fragments (edge = r, k-chunk = quad) ----
        const int ei = eidx[e0 + r];
        const int ej = eidx[NE + e0 + r];
        const float* xi = x + (size_t)ei * DD;
        const float* xj = x + (size_t)ej * DD;
        const float* ev = ea + (size_t)(e0 + r) * DD;

        bf16x8 Ahi[6], Alo[6];  // 0,1: x_i k-tiles; 2,3: x_j; 4,5: ea
        load8(xi + q * 8,      Ahi[0], Alo[0]);
        load8(xi + 32 + q * 8, Ahi[1], Alo[1]);
        load8(xj + q * 8,      Ahi[2], Alo[2]);
        load8(xj + 32 + q * 8, Ahi[3], Alo[3]);
        load8(ev + q * 8,      Ahi[4], Alo[4]);
        load8(ev + 32 + q * 8, Ahi[5], Alo[5]);

        f32x4 aci[16], acj[16];
#pragma unroll
        for (int nt = 0; nt < 16; ++nt) {
            aci[nt] = (f32x4){0.f, 0.f, 0.f, 0.f};
            acj[nt] = (f32x4){0.f, 0.f, 0.f, 0.f};
        }

        // ---- MFMA K-loop: 16 col-tiles x 4 k-tiles, hi+lo compensated A ----
#pragma unroll
        for (int nt = 0; nt < 16; ++nt) {
            const unsigned short* bp = &Wsh[(nt * 16 + r) * WT_LD + q * 8];
#pragma unroll
            for (int kt = 0; kt < 4; ++kt) {
                bf16x8 bf = *(const bf16x8*)(bp + kt * 32);
                const int fi = (kt < 2) ? kt : kt + 2;  // x_i, x_i, ea, ea
                const int fj = kt + 2;                  // x_j, x_j, ea, ea
                aci[nt] = __builtin_amdgcn_mfma_f32_16x16x32_bf16(Ahi[fi], bf, aci[nt], 0, 0, 0);
                aci[nt] = __builtin_amdgcn_mfma_f32_16x16x32_bf16(Alo[fi], bf, aci[nt], 0, 0, 0);
                acj[nt] = __builtin_amdgcn_mfma_f32_16x16x32_bf16(Ahi[fj], bf, acj[nt], 0, 0, 0);
                acj[nt] = __builtin_amdgcn_mfma_f32_16x16x32_bf16(Alo[fj], bf, acj[nt], 0, 0, 0);
            }
        }

        // ---- epilogue ----
        // C layout: col = nt*16 + r, row(edge-local) = q*4 + reg.
        float lg[4][4];  // [reg][head]
#pragma unroll
        for (int a = 0; a < 4; ++a)
#pragma unroll
            for (int b = 0; b < 4; ++b) lg[a][b] = 0.f;

#pragma unroll
        for (int nt = 0; nt < 16; ++nt) {
            const float ai = attI[nt * 16 + r];
            const float aj = attJ[nt * 16 + r];
            const int h = nt >> 2;
#pragma unroll
            for (int reg = 0; reg < 4; ++reg) {
                float spi = softplus_f(aci[nt][reg]);
                float spj = softplus_f(acj[nt][reg]);
                acj[nt][reg] = spj;  // keep post-softplus out_j
                lg[reg][h] += spi * ai + spj * aj;
            }
        }
        // reduce over the 16 lanes (r) sharing the same 4 edges
#pragma unroll
        for (int off = 1; off < 16; off <<= 1) {
#pragma unroll
            for (int a = 0; a < 4; ++a)
#pragma unroll
                for (int b = 0; b < 4; ++b)
                    lg[a][b] += __shfl_xor(lg[a][b], off, 64);
        }
        float exv[4][4];
#pragma unroll
        for (int reg = 0; reg < 4; ++reg)
#pragma unroll
            for (int h = 0; h < 4; ++h)
                exv[reg][h] = __expf(softplus_f(fmaf(lg[reg][h], bnsc[h], bnsh[h])));

        if (r < 4) {  // lane r handles head r for its quad's 4 edges
#pragma unroll
            for (int reg = 0; reg < 4; ++reg) {
                const int e = e0 + q * 4 + reg;
                const int ii = eidx[e];
                expa[e * 4 + r] = exv[reg][r];
                atomicAdd(&denom[ii * 4 + r], exv[reg][r]);
            }
        }
        // out_j bf16 store, layout [e][d][h]: offset e*256 + d*4 + h
#pragma unroll
        for (int reg = 0; reg < 4; ++reg) {
            const unsigned e = (unsigned)(e0 + q * 4 + reg);
#pragma unroll
            for (int dt = 0; dt < 4; ++dt) {
                ushort4 pk;
                pk.x = f2bf(acj[dt][reg]);
                pk.y = f2bf(acj[4 + dt][reg]);
                pk.z = f2bf(acj[8 + dt][reg]);
                pk.w = f2bf(acj[12 + dt][reg]);
                *(ushort4*)&outj[e * 256 + (dt * 16 + r) * 4] = pk;
            }
        }
    }
}

// One wave per edge; lane = output dim d. Mean over heads folded in (0.25).
__global__ __launch_bounds__(256)
void k_scatter(const int* __restrict__ eidx,
               const unsigned short* __restrict__ outj,
               const float* __restrict__ expa,
               const float* __restrict__ denom,
               float* __restrict__ acc)
{
    const int e = blockIdx.x * 4 + (threadIdx.x >> 6);
    const int lane = threadIdx.x & 63;
    const int i = eidx[e];
    float4 ev = *(const float4*)&expa[e * 4];
    float4 dv = *(const float4*)&denom[i * 4];
    float w0 = 0.25f * ev.x / dv.x;
    float w1 = 0.25f * ev.y / dv.y;
    float w2 = 0.25f * ev.z / dv.z;
    float w3 = 0.25f * ev.w / dv.w;
    ushort4 v = *(const ushort4*)&outj[((unsigned)e << 8) | (lane << 2)];
    float s = w0 * bf2f(v.x) + w1 * bf2f(v.y) + w2 * bf2f(v.z) + w3 * bf2f(v.w);
    atomicAdd(&acc[i * DD + lane], s);
}

__global__ __launch_bounds__(256)
void k_final(const float* __restrict__ acc, const float* __restrict__ bias,
             float* __restrict__ out)
{
    const int t = blockIdx.x * 256 + threadIdx.x;
    out[t] = acc[t] + bias[t & 63];
}

extern "C" void kernel_launch(void* const* d_in, const int* in_sizes, int n_in,
                              void* d_out, int out_size, void* d_ws, size_t ws_size,
                              hipStream_t stream)
{
    (void)in_sizes; (void)n_in; (void)out_size; (void)ws_size;
    const float* x    = (const float*)d_in[0];
    const float* ea   = (const float*)d_in[1];
    const float* W    = (const float*)d_in[2];
    const float* att  = (const float*)d_in[3];
    const float* bias = (const float*)d_in[4];
    const float* bn_g = (const float*)d_in[5];
    const float* bn_b = (const float*)d_in[6];
    const float* bn_m = (const float*)d_in[7];
    const float* bn_v = (const float*)d_in[8];
    const int*   eidx = (const int*)d_in[9];
    float* out = (float*)d_out;

    // ws layout: outj bf16 [E][64][4] (128 MB) | expa f32 [E][4] | denom f32 [N][4] | acc f32 [N][64]
    char* ws = (char*)d_ws;
    unsigned short* outj = (unsigned short*)ws;
    float* expa  = (float*)(ws + (size_t)NE * 256 * 2);
    float* denom = (float*)(ws + (size_t)NE * 256 * 2 + (size_t)NE * 16);
    float* acc   = denom + (size_t)NN * 4;

    hipMemsetAsync(denom, 0, (size_t)(NN * 4 + NN * DD) * sizeof(float), stream);

    k_edge<<<dim3(512), dim3(256), 0, stream>>>(
        x, ea, W, att, bn_g, bn_b, bn_m, bn_v, eidx, outj, expa, denom);
    k_scatter<<<dim3(NE / 4), dim3(256), 0, stream>>>(eidx, outj, expa, denom, acc);
    k_final<<<dim3((NN * DD) / 256), dim3(256), 0, stream>>>(acc, bias, out);
}